// Round 4
// baseline (619.591 us; speedup 1.0000x reference)
//
#include <hip/hip_runtime.h>

#define NODE 128
#define EQUI 480
#define CATD 352
#define OUTD 608
#define RPB  32          // rows per block
#define SA   360         // LDS row stride in bf16 elems: 180 dwords, 180%32=20 -> 2-way bank alias (free)
#define NTILES 22        // 352/16
#define KSTEPS 11        // 352/32
#define EPSF 1e-5f

typedef __bf16 bfv8 __attribute__((ext_vector_type(8)));
typedef float  f32x4 __attribute__((ext_vector_type(4)));

__device__ __forceinline__ unsigned short f2bf(float f) {
  unsigned int u = __builtin_bit_cast(unsigned int, f);
  u += 0x7FFFu + ((u >> 16) & 1u);          // round-to-nearest-even
  return (unsigned short)(u >> 16);
}

// Cast + transpose W1, W2 (fp32 [k][j] row-major) -> bf16 W^T [j][k] in ws.
__global__ void prep_kernel(const float* __restrict__ W1, const float* __restrict__ W2,
                            unsigned short* __restrict__ WT) {
  int idx = blockIdx.x * 256 + threadIdx.x;
  if (idx >= 2 * CATD * CATD) return;
  int which = (idx >= CATD * CATD);
  int rr = which ? idx - CATD * CATD : idx;
  int j = rr / CATD, k = rr - j * CATD;
  const float* W = which ? W2 : W1;
  WT[idx] = f2bf(W[k * CATD + j]);
}

__global__ __launch_bounds__(512, 4) void fused_kernel(
    const float* __restrict__ node_scalar, const float* __restrict__ node_equi,
    const float* __restrict__ ln_w, const float* __restrict__ ln_b,
    const unsigned short* __restrict__ W1T, const unsigned short* __restrict__ W2T,
    const float* __restrict__ b1, const float* __restrict__ b2,
    float* __restrict__ out, int N) {

  __shared__ __attribute__((aligned(16))) unsigned short sA[RPB * SA]; // cat (bf16)
  __shared__ __attribute__((aligned(16))) unsigned short sH[RPB * SA]; // silu(h1) (bf16)
  __shared__ float sMean0[RPB], sS0[RPB], sS1[RPB], sS2[RPB];

  const int tid  = threadIdx.x;
  const long row0 = (long)blockIdx.x * RPB;

  // ---------------- Phase 1: LN + equivariant norms -> cat in LDS ----------------
  // Waves 0-3 only (8 threads per row x 32 rows); waves 4-7 wait at the barrier.
  if (tid < 256) {
    const int r = tid >> 3, g = tid & 7;   // 8 threads per row, same wave
    const long row_g = row0 + r;
    if (row_g < N) {
      float lv[16];
      float s = 0.f, q = 0.f;
      // LayerNorm over node_scalar[128]
      const float* xs = node_scalar + row_g * NODE;
      #pragma unroll
      for (int i = 0; i < 4; i++) {
        float4 t = *(const float4*)(xs + g * 16 + i * 4);
        lv[i*4+0] = t.x; lv[i*4+1] = t.y; lv[i*4+2] = t.z; lv[i*4+3] = t.w;
        s += t.x + t.y + t.z + t.w;
        q += t.x*t.x + t.y*t.y + t.z*t.z + t.w*t.w;
      }
      #pragma unroll
      for (int m = 1; m < 8; m <<= 1) { s += __shfl_xor(s, m, 64); q += __shfl_xor(q, m, 64); }
      float mean = s * (1.f / NODE);
      float rstd = rsqrtf(q * (1.f / NODE) - mean * mean + EPSF);
      #pragma unroll
      for (int i = 0; i < 16; i++) {
        int c = g * 16 + i;
        sA[r * SA + c] = f2bf((lv[i] - mean) * rstd * ln_w[c] + ln_b[c]);
      }
      const float* xe = node_equi + row_g * EQUI;
      // l=0 (mul=128, d=1): center over mul, RMS, inv = eb^2
      s = 0.f; q = 0.f;
      #pragma unroll
      for (int i = 0; i < 4; i++) {
        float4 t = *(const float4*)(xe + g * 16 + i * 4);
        lv[i*4+0] = t.x; lv[i*4+1] = t.y; lv[i*4+2] = t.z; lv[i*4+3] = t.w;
        s += t.x + t.y + t.z + t.w;
        q += t.x*t.x + t.y*t.y + t.z*t.z + t.w*t.w;
      }
      #pragma unroll
      for (int m = 1; m < 8; m <<= 1) { s += __shfl_xor(s, m, 64); q += __shfl_xor(q, m, 64); }
      float mean0 = s * (1.f / 128.f);
      float s0 = rsqrtf(q * (1.f / 128.f) - mean0 * mean0 + EPSF);
      #pragma unroll
      for (int i = 0; i < 16; i++) {
        float e = (lv[i] - mean0) * s0;
        sA[r * SA + NODE + g * 16 + i] = f2bf(e * e);
      }
      if (g == 0) { sMean0[r] = mean0; sS0[r] = s0; }
      // l=1 (mul=64, d=3)
      float a1[24]; q = 0.f;
      #pragma unroll
      for (int i = 0; i < 6; i++) {
        float4 t = *(const float4*)(xe + 128 + g * 24 + i * 4);
        a1[i*4+0] = t.x; a1[i*4+1] = t.y; a1[i*4+2] = t.z; a1[i*4+3] = t.w;
        q += t.x*t.x + t.y*t.y + t.z*t.z + t.w*t.w;
      }
      #pragma unroll
      for (int m = 1; m < 8; m <<= 1) q += __shfl_xor(q, m, 64);
      float s1 = rsqrtf(q * (1.f / 64.f) + EPSF);
      float s1q = s1 * s1 * 0.57735026919f; // 1/sqrt(3)
      #pragma unroll
      for (int mi = 0; mi < 8; mi++) {
        float ss = a1[mi*3]*a1[mi*3] + a1[mi*3+1]*a1[mi*3+1] + a1[mi*3+2]*a1[mi*3+2];
        sA[r * SA + 256 + g * 8 + mi] = f2bf(ss * s1q);
      }
      if (g == 0) sS1[r] = s1;
      // l=2 (mul=32, d=5)
      float a2[20]; q = 0.f;
      #pragma unroll
      for (int i = 0; i < 5; i++) {
        float4 t = *(const float4*)(xe + 320 + g * 20 + i * 4);
        a2[i*4+0] = t.x; a2[i*4+1] = t.y; a2[i*4+2] = t.z; a2[i*4+3] = t.w;
        q += t.x*t.x + t.y*t.y + t.z*t.z + t.w*t.w;
      }
      #pragma unroll
      for (int m = 1; m < 8; m <<= 1) q += __shfl_xor(q, m, 64);
      float s2 = rsqrtf(q * (1.f / 32.f) + EPSF);
      float s2q = s2 * s2 * 0.44721359549f; // 1/sqrt(5)
      #pragma unroll
      for (int mi = 0; mi < 4; mi++) {
        float ss = a2[mi*5]*a2[mi*5] + a2[mi*5+1]*a2[mi*5+1] + a2[mi*5+2]*a2[mi*5+2]
                 + a2[mi*5+3]*a2[mi*5+3] + a2[mi*5+4]*a2[mi*5+4];
        sA[r * SA + 320 + g * 4 + mi] = f2bf(ss * s2q);
      }
      if (g == 0) sS2[r] = s2;
    }
  }
  __syncthreads();

  const int lane = tid & 63, wv = tid >> 6;      // wv in 0..7
  const int ml = lane & 15, quad = lane >> 4;
  const int koff = quad * 8;

  // ---------------- GEMM1: h1 = silu(cat @ W1 + b1) -> LDS bf16 ----------------
  for (int nt = wv; nt < NTILES; nt += 8) {
    f32x4 acc0  = {0.f, 0.f, 0.f, 0.f};
    f32x4 acc1  = {0.f, 0.f, 0.f, 0.f};
    f32x4 acc0b = {0.f, 0.f, 0.f, 0.f};
    f32x4 acc1b = {0.f, 0.f, 0.f, 0.f};
    const unsigned short* Bp = W1T + (nt * 16 + ml) * CATD + koff;
    const unsigned short* A0 = &sA[ml * SA + koff];
    const unsigned short* A1 = &sA[(ml + 16) * SA + koff];
    #pragma unroll
    for (int ks = 0; ks < KSTEPS; ks++) {
      bfv8 b  = *(const bfv8*)(Bp + ks * 32);
      bfv8 a0 = *(const bfv8*)(A0 + ks * 32);
      bfv8 a1 = *(const bfv8*)(A1 + ks * 32);
      if (ks & 1) {   // compile-time constant under full unroll: 2 independent chains
        acc0b = __builtin_amdgcn_mfma_f32_16x16x32_bf16(a0, b, acc0b, 0, 0, 0);
        acc1b = __builtin_amdgcn_mfma_f32_16x16x32_bf16(a1, b, acc1b, 0, 0, 0);
      } else {
        acc0 = __builtin_amdgcn_mfma_f32_16x16x32_bf16(a0, b, acc0, 0, 0, 0);
        acc1 = __builtin_amdgcn_mfma_f32_16x16x32_bf16(a1, b, acc1, 0, 0, 0);
      }
    }
    acc0 += acc0b;
    acc1 += acc1b;
    const int col = nt * 16 + ml;
    const float bb = b1[col];
    #pragma unroll
    for (int reg = 0; reg < 4; reg++) {
      int rr = quad * 4 + reg;
      float v0 = acc0[reg] + bb; v0 = v0 / (1.f + __expf(-v0));
      sH[rr * SA + col] = f2bf(v0);
      float v1 = acc1[reg] + bb; v1 = v1 / (1.f + __expf(-v1));
      sH[(rr + 16) * SA + col] = f2bf(v1);
    }
  }
  __syncthreads();

  // ---------------- GEMM2 + fused gating epilogue (from accumulators) ----------------
  for (int nt = wv; nt < NTILES; nt += 8) {
    f32x4 acc0  = {0.f, 0.f, 0.f, 0.f};
    f32x4 acc1  = {0.f, 0.f, 0.f, 0.f};
    f32x4 acc0b = {0.f, 0.f, 0.f, 0.f};
    f32x4 acc1b = {0.f, 0.f, 0.f, 0.f};
    const unsigned short* Bp = W2T + (nt * 16 + ml) * CATD + koff;
    const unsigned short* A0 = &sH[ml * SA + koff];
    const unsigned short* A1 = &sH[(ml + 16) * SA + koff];
    #pragma unroll
    for (int ks = 0; ks < KSTEPS; ks++) {
      bfv8 b  = *(const bfv8*)(Bp + ks * 32);
      bfv8 a0 = *(const bfv8*)(A0 + ks * 32);
      bfv8 a1 = *(const bfv8*)(A1 + ks * 32);
      if (ks & 1) {
        acc0b = __builtin_amdgcn_mfma_f32_16x16x32_bf16(a0, b, acc0b, 0, 0, 0);
        acc1b = __builtin_amdgcn_mfma_f32_16x16x32_bf16(a1, b, acc1b, 0, 0, 0);
      } else {
        acc0 = __builtin_amdgcn_mfma_f32_16x16x32_bf16(a0, b, acc0, 0, 0, 0);
        acc1 = __builtin_amdgcn_mfma_f32_16x16x32_bf16(a1, b, acc1, 0, 0, 0);
      }
    }
    acc0 += acc0b;
    acc1 += acc1b;
    const int col = nt * 16 + ml;
    const float bb = b2[col];
    #pragma unroll
    for (int half = 0; half < 2; half++) {
      #pragma unroll
      for (int reg = 0; reg < 4; reg++) {
        const int r = half * 16 + quad * 4 + reg;
        const long row_g = row0 + r;
        if (row_g >= N) continue;
        float val = (half ? acc1[reg] : acc0[reg]) + bb;
        float* orow = out + row_g * OUTD;
        if (col < 128) {                       // d_scalar
          orow[col] = node_scalar[row_g * NODE + col] + val;
        } else if (col < 256) {                // l=0 gate
          const int c = col - 128;
          float x = node_equi[row_g * EQUI + c];
          orow[NODE + c] = x + (x - sMean0[r]) * sS0[r] * val;
        } else if (col < 320) {                // l=1 gate
          const int i3 = col - 256; const int c0 = 128 + i3 * 3;
          const float f = 1.f + sS1[r] * val;
          #pragma unroll
          for (int d = 0; d < 3; d++) {
            float x = node_equi[row_g * EQUI + c0 + d];
            orow[NODE + c0 + d] = x * f;
          }
        } else {                               // l=2 gate
          const int i5 = col - 320; const int c0 = 320 + i5 * 5;
          const float f = 1.f + sS2[r] * val;
          #pragma unroll
          for (int d = 0; d < 5; d++) {
            float x = node_equi[row_g * EQUI + c0 + d];
            orow[NODE + c0 + d] = x * f;
          }
        }
      }
    }
  }
}

extern "C" void kernel_launch(void* const* d_in, const int* in_sizes, int n_in,
                              void* d_out, int out_size, void* d_ws, size_t ws_size,
                              hipStream_t stream) {
  const float* node_scalar = (const float*)d_in[0];
  const float* node_equi   = (const float*)d_in[1];
  const float* ln_w = (const float*)d_in[2];
  const float* ln_b = (const float*)d_in[3];
  const float* W1   = (const float*)d_in[4];
  const float* b1   = (const float*)d_in[5];
  const float* W2   = (const float*)d_in[6];
  const float* b2   = (const float*)d_in[7];
  float* out = (float*)d_out;
  const int N = in_sizes[0] / NODE;

  unsigned short* WT = (unsigned short*)d_ws;      // W1T at 0, W2T at 352*352
  const int prep_elems = 2 * CATD * CATD;
  prep_kernel<<<(prep_elems + 255) / 256, 256, 0, stream>>>(W1, W2, WT);

  const int nblk = (N + RPB - 1) / RPB;
  fused_kernel<<<nblk, 512, 0, stream>>>(node_scalar, node_equi, ln_w, ln_b,
                                         WT, WT + CATD * CATD, b1, b2, out, N);
}

// Round 5
// 548.233 us; speedup vs baseline: 1.1302x; 1.1302x over previous
//
#include <hip/hip_runtime.h>

#define NODE 128
#define EQUI 480
#define CATD 352
#define OUTD 608
#define RPB  32          // rows per block
#define SA   360         // LDS row stride in bf16 elems: 180 dwords, 180%32=20 -> 2-way bank alias (free)
#define NTILES 22        // 352/16
#define KSTEPS 11        // 352/32
#define EPSF 1e-5f

typedef __bf16 bfv8 __attribute__((ext_vector_type(8)));
typedef float  f32x4 __attribute__((ext_vector_type(4)));

__device__ __forceinline__ unsigned short f2bf(float f) {
  unsigned int u = __builtin_bit_cast(unsigned int, f);
  u += 0x7FFFu + ((u >> 16) & 1u);          // round-to-nearest-even
  return (unsigned short)(u >> 16);
}

__device__ __forceinline__ float bf2f(unsigned short u) {
  return __builtin_bit_cast(float, (unsigned int)u << 16);
}

__device__ __forceinline__ float silu_f(float v) { return v / (1.f + __expf(-v)); }

// Cast + transpose W1, W2 (fp32 [k][j] row-major) -> bf16 W^T [j][k] in ws.
__global__ void prep_kernel(const float* __restrict__ W1, const float* __restrict__ W2,
                            unsigned short* __restrict__ WT) {
  int idx = blockIdx.x * 256 + threadIdx.x;
  if (idx >= 2 * CATD * CATD) return;
  int which = (idx >= CATD * CATD);
  int rr = which ? idx - CATD * CATD : idx;
  int j = rr / CATD, k = rr - j * CATD;
  const float* W = which ? W2 : W1;
  WT[idx] = f2bf(W[k * CATD + j]);
}

__global__ __launch_bounds__(256, 2) void fused_kernel(
    const float* __restrict__ node_scalar, const float* __restrict__ node_equi,
    const float* __restrict__ ln_w, const float* __restrict__ ln_b,
    const unsigned short* __restrict__ W1T, const unsigned short* __restrict__ W2T,
    const float* __restrict__ b1, const float* __restrict__ b2,
    float* __restrict__ out, int N) {

  __shared__ __attribute__((aligned(16))) unsigned short sA[RPB * SA]; // cat; then h2 staging
  __shared__ __attribute__((aligned(16))) unsigned short sH[RPB * SA]; // silu(h1) (bf16)
  __shared__ float sMean0[RPB], sS0[RPB], sS1[RPB], sS2[RPB];

  const int tid  = threadIdx.x;
  const long row0 = (long)blockIdx.x * RPB;

  // ---------------- Phase 1: LN + equivariant norms -> cat in LDS ----------------
  {
    const int r = tid >> 3, g = tid & 7;   // 8 threads per row, same wave
    const long row_g = row0 + r;
    if (row_g < N) {
      float lv[16];
      float s = 0.f, q = 0.f;
      // LayerNorm over node_scalar[128]
      const float* xs = node_scalar + row_g * NODE;
      #pragma unroll
      for (int i = 0; i < 4; i++) {
        float4 t = *(const float4*)(xs + g * 16 + i * 4);
        lv[i*4+0] = t.x; lv[i*4+1] = t.y; lv[i*4+2] = t.z; lv[i*4+3] = t.w;
        s += t.x + t.y + t.z + t.w;
        q += t.x*t.x + t.y*t.y + t.z*t.z + t.w*t.w;
      }
      #pragma unroll
      for (int m = 1; m < 8; m <<= 1) { s += __shfl_xor(s, m, 64); q += __shfl_xor(q, m, 64); }
      float mean = s * (1.f / NODE);
      float rstd = rsqrtf(q * (1.f / NODE) - mean * mean + EPSF);
      #pragma unroll
      for (int i = 0; i < 16; i++) {
        int c = g * 16 + i;
        sA[r * SA + c] = f2bf((lv[i] - mean) * rstd * ln_w[c] + ln_b[c]);
      }
      const float* xe = node_equi + row_g * EQUI;
      // l=0 (mul=128, d=1): center over mul, RMS, inv = eb^2
      s = 0.f; q = 0.f;
      #pragma unroll
      for (int i = 0; i < 4; i++) {
        float4 t = *(const float4*)(xe + g * 16 + i * 4);
        lv[i*4+0] = t.x; lv[i*4+1] = t.y; lv[i*4+2] = t.z; lv[i*4+3] = t.w;
        s += t.x + t.y + t.z + t.w;
        q += t.x*t.x + t.y*t.y + t.z*t.z + t.w*t.w;
      }
      #pragma unroll
      for (int m = 1; m < 8; m <<= 1) { s += __shfl_xor(s, m, 64); q += __shfl_xor(q, m, 64); }
      float mean0 = s * (1.f / 128.f);
      float s0 = rsqrtf(q * (1.f / 128.f) - mean0 * mean0 + EPSF);
      #pragma unroll
      for (int i = 0; i < 16; i++) {
        float e = (lv[i] - mean0) * s0;
        sA[r * SA + NODE + g * 16 + i] = f2bf(e * e);
      }
      if (g == 0) { sMean0[r] = mean0; sS0[r] = s0; }
      // l=1 (mul=64, d=3)
      float a1[24]; q = 0.f;
      #pragma unroll
      for (int i = 0; i < 6; i++) {
        float4 t = *(const float4*)(xe + 128 + g * 24 + i * 4);
        a1[i*4+0] = t.x; a1[i*4+1] = t.y; a1[i*4+2] = t.z; a1[i*4+3] = t.w;
        q += t.x*t.x + t.y*t.y + t.z*t.z + t.w*t.w;
      }
      #pragma unroll
      for (int m = 1; m < 8; m <<= 1) q += __shfl_xor(q, m, 64);
      float s1 = rsqrtf(q * (1.f / 64.f) + EPSF);
      float s1q = s1 * s1 * 0.57735026919f; // 1/sqrt(3)
      #pragma unroll
      for (int mi = 0; mi < 8; mi++) {
        float ss = a1[mi*3]*a1[mi*3] + a1[mi*3+1]*a1[mi*3+1] + a1[mi*3+2]*a1[mi*3+2];
        sA[r * SA + 256 + g * 8 + mi] = f2bf(ss * s1q);
      }
      if (g == 0) sS1[r] = s1;
      // l=2 (mul=32, d=5)
      float a2[20]; q = 0.f;
      #pragma unroll
      for (int i = 0; i < 5; i++) {
        float4 t = *(const float4*)(xe + 320 + g * 20 + i * 4);
        a2[i*4+0] = t.x; a2[i*4+1] = t.y; a2[i*4+2] = t.z; a2[i*4+3] = t.w;
        q += t.x*t.x + t.y*t.y + t.z*t.z + t.w*t.w;
      }
      #pragma unroll
      for (int m = 1; m < 8; m <<= 1) q += __shfl_xor(q, m, 64);
      float s2 = rsqrtf(q * (1.f / 32.f) + EPSF);
      float s2q = s2 * s2 * 0.44721359549f; // 1/sqrt(5)
      #pragma unroll
      for (int mi = 0; mi < 4; mi++) {
        float ss = a2[mi*5]*a2[mi*5] + a2[mi*5+1]*a2[mi*5+1] + a2[mi*5+2]*a2[mi*5+2]
                 + a2[mi*5+3]*a2[mi*5+3] + a2[mi*5+4]*a2[mi*5+4];
        sA[r * SA + 320 + g * 4 + mi] = f2bf(ss * s2q);
      }
      if (g == 0) sS2[r] = s2;
    }
  }
  __syncthreads();

  const int lane = tid & 63, wv = tid >> 6;
  const int ml = lane & 15, quad = lane >> 4;
  const int koff = quad * 8;

  // ---------------- GEMM1: h1 = silu(cat @ W1 + b1) -> LDS bf16 ----------------
  for (int nt = wv; nt < NTILES; nt += 4) {
    f32x4 acc0  = {0.f, 0.f, 0.f, 0.f};
    f32x4 acc1  = {0.f, 0.f, 0.f, 0.f};
    f32x4 acc0b = {0.f, 0.f, 0.f, 0.f};
    f32x4 acc1b = {0.f, 0.f, 0.f, 0.f};
    const unsigned short* Bp = W1T + (nt * 16 + ml) * CATD + koff;
    const unsigned short* A0 = &sA[ml * SA + koff];
    const unsigned short* A1 = &sA[(ml + 16) * SA + koff];
    #pragma unroll
    for (int ks = 0; ks < KSTEPS; ks++) {
      bfv8 b  = *(const bfv8*)(Bp + ks * 32);
      bfv8 a0 = *(const bfv8*)(A0 + ks * 32);
      bfv8 a1 = *(const bfv8*)(A1 + ks * 32);
      if (ks & 1) {   // compile-time constant under full unroll: 2 independent chains
        acc0b = __builtin_amdgcn_mfma_f32_16x16x32_bf16(a0, b, acc0b, 0, 0, 0);
        acc1b = __builtin_amdgcn_mfma_f32_16x16x32_bf16(a1, b, acc1b, 0, 0, 0);
      } else {
        acc0 = __builtin_amdgcn_mfma_f32_16x16x32_bf16(a0, b, acc0, 0, 0, 0);
        acc1 = __builtin_amdgcn_mfma_f32_16x16x32_bf16(a1, b, acc1, 0, 0, 0);
      }
    }
    acc0 += acc0b;
    acc1 += acc1b;
    const int col = nt * 16 + ml;
    const float bb = b1[col];
    #pragma unroll
    for (int reg = 0; reg < 4; reg++) {
      int rr = quad * 4 + reg;
      float v0 = acc0[reg] + bb; v0 = silu_f(v0);
      sH[rr * SA + col] = f2bf(v0);
      float v1 = acc1[reg] + bb; v1 = silu_f(v1);
      sH[(rr + 16) * SA + col] = f2bf(v1);
    }
  }
  __syncthreads();

  // ---------------- GEMM2: h2 = h1 @ W2 + b2 -> stage bf16 into sA (dead) ----------------
  for (int nt = wv; nt < NTILES; nt += 4) {
    f32x4 acc0  = {0.f, 0.f, 0.f, 0.f};
    f32x4 acc1  = {0.f, 0.f, 0.f, 0.f};
    f32x4 acc0b = {0.f, 0.f, 0.f, 0.f};
    f32x4 acc1b = {0.f, 0.f, 0.f, 0.f};
    const unsigned short* Bp = W2T + (nt * 16 + ml) * CATD + koff;
    const unsigned short* A0 = &sH[ml * SA + koff];
    const unsigned short* A1 = &sH[(ml + 16) * SA + koff];
    #pragma unroll
    for (int ks = 0; ks < KSTEPS; ks++) {
      bfv8 b  = *(const bfv8*)(Bp + ks * 32);
      bfv8 a0 = *(const bfv8*)(A0 + ks * 32);
      bfv8 a1 = *(const bfv8*)(A1 + ks * 32);
      if (ks & 1) {
        acc0b = __builtin_amdgcn_mfma_f32_16x16x32_bf16(a0, b, acc0b, 0, 0, 0);
        acc1b = __builtin_amdgcn_mfma_f32_16x16x32_bf16(a1, b, acc1b, 0, 0, 0);
      } else {
        acc0 = __builtin_amdgcn_mfma_f32_16x16x32_bf16(a0, b, acc0, 0, 0, 0);
        acc1 = __builtin_amdgcn_mfma_f32_16x16x32_bf16(a1, b, acc1, 0, 0, 0);
      }
    }
    acc0 += acc0b;
    acc1 += acc1b;
    const int col = nt * 16 + ml;
    const float bb = b2[col];
    #pragma unroll
    for (int reg = 0; reg < 4; reg++) {
      int rr = quad * 4 + reg;
      sA[rr * SA + col]        = f2bf(acc0[reg] + bb);   // sA dead since GEMM1 barrier
      sA[(rr + 16) * SA + col] = f2bf(acc1[reg] + bb);
    }
  }
  __syncthreads();

  // ---------------- Row-parallel epilogue: fully coalesced float4 loads/stores ----------------
  {
    const int r = tid >> 3, g = tid & 7;   // same mapping as phase 1
    const long row_g = row0 + r;
    if (row_g < N) {
      const float mean0 = sMean0[r], s0 = sS0[r], s1 = sS1[r], s2 = sS2[r];
      const float* xs = node_scalar + row_g * NODE;
      const float* xe = node_equi + row_g * EQUI;
      float* orow = out + row_g * OUTD;
      const unsigned short* h2 = &sA[r * SA];

      // Region A: d_scalar (out cols 0..127) <- h2[0..127]
      #pragma unroll
      for (int i = 0; i < 4; i++) {
        const int c = g * 16 + i * 4;
        float4 t = *(const float4*)(xs + c);
        float4 o;
        o.x = t.x + bf2f(h2[c + 0]);
        o.y = t.y + bf2f(h2[c + 1]);
        o.z = t.z + bf2f(h2[c + 2]);
        o.w = t.w + bf2f(h2[c + 3]);
        *(float4*)(orow + c) = o;
      }
      // Region B: l=0 gate (out cols 128..255) <- h2[128..255], equi[0..127]
      #pragma unroll
      for (int i = 0; i < 4; i++) {
        const int c = g * 16 + i * 4;
        float4 t = *(const float4*)(xe + c);
        float4 o;
        o.x = t.x + (t.x - mean0) * s0 * bf2f(h2[128 + c + 0]);
        o.y = t.y + (t.y - mean0) * s0 * bf2f(h2[128 + c + 1]);
        o.z = t.z + (t.z - mean0) * s0 * bf2f(h2[128 + c + 2]);
        o.w = t.w + (t.w - mean0) * s0 * bf2f(h2[128 + c + 3]);
        *(float4*)(orow + 128 + c) = o;
      }
      // Region C: l=1 gate (out cols 256..447) <- gates h2[256..319], equi[128..319]
      float gv[8];
      #pragma unroll
      for (int i = 0; i < 8; i++) gv[i] = 1.f + s1 * bf2f(h2[256 + g * 8 + i]);
      #pragma unroll
      for (int i = 0; i < 6; i++) {
        const int j = g * 24 + i * 4;          // j % 24 pattern; gate idx = (i*4+k)/3 local
        float4 t = *(const float4*)(xe + 128 + j);
        float4 o;
        o.x = t.x * gv[(i * 4 + 0) / 3];
        o.y = t.y * gv[(i * 4 + 1) / 3];
        o.z = t.z * gv[(i * 4 + 2) / 3];
        o.w = t.w * gv[(i * 4 + 3) / 3];
        *(float4*)(orow + 256 + j) = o;
      }
      // Region D: l=2 gate (out cols 448..607) <- gates h2[320..351], equi[320..479]
      float hv[4];
      #pragma unroll
      for (int i = 0; i < 4; i++) hv[i] = 1.f + s2 * bf2f(h2[320 + g * 4 + i]);
      #pragma unroll
      for (int i = 0; i < 5; i++) {
        const int j = g * 20 + i * 4;
        float4 t = *(const float4*)(xe + 320 + j);
        float4 o;
        o.x = t.x * hv[(i * 4 + 0) / 5];
        o.y = t.y * hv[(i * 4 + 1) / 5];
        o.z = t.z * hv[(i * 4 + 2) / 5];
        o.w = t.w * hv[(i * 4 + 3) / 5];
        *(float4*)(orow + 448 + j) = o;
      }
    }
  }
}

extern "C" void kernel_launch(void* const* d_in, const int* in_sizes, int n_in,
                              void* d_out, int out_size, void* d_ws, size_t ws_size,
                              hipStream_t stream) {
  const float* node_scalar = (const float*)d_in[0];
  const float* node_equi   = (const float*)d_in[1];
  const float* ln_w = (const float*)d_in[2];
  const float* ln_b = (const float*)d_in[3];
  const float* W1   = (const float*)d_in[4];
  const float* b1   = (const float*)d_in[5];
  const float* W2   = (const float*)d_in[6];
  const float* b2   = (const float*)d_in[7];
  float* out = (float*)d_out;
  const int N = in_sizes[0] / NODE;

  unsigned short* WT = (unsigned short*)d_ws;      // W1T at 0, W2T at 352*352
  const int prep_elems = 2 * CATD * CATD;
  prep_kernel<<<(prep_elems + 255) / 256, 256, 0, stream>>>(W1, W2, WT);

  const int nblk = (N + RPB - 1) / RPB;
  fused_kernel<<<nblk, 256, 0, stream>>>(node_scalar, node_equi, ln_w, ln_b,
                                         WT, WT + CATD * CATD, b1, b2, out, N);
}